// Round 1
// baseline (257.349 us; speedup 1.0000x reference)
//
#include <hip/hip_runtime.h>
#include <math.h>

// AttentionPooling: B=128, S=2048, D=128, NQ=18, QDIM=100 (fp32)
// Kernel 1: per (batch, S-chunk) split-softmax partials (m, l, unnorm acc)
// Kernel 2: merge partials, normalize, write out.

#define BB 128
#define SS 2048
#define DD 128
#define NQ 18
#define NCHUNK 4
#define CHUNK 512            // SS / NCHUNK
#define SCALE 0.08838834764831845f   // 1/sqrt(128)
#define REC_F (NQ * 2 + NQ * DD)     // per-(b,c) record: m[18], l[18], acc[18][128]
#define ACC_OFF (NQ * 2)

__global__ __launch_bounds__(256) void ap_partial(
    const float* __restrict__ x, const float* __restrict__ q_emb,
    const int* __restrict__ questions, const int* __restrict__ mask,
    float* __restrict__ ws)
{
    __shared__ float q_lds[NQ * DD];      // 9 KB
    __shared__ float s_lds[NQ * CHUNK];   // 36 KB
    __shared__ int   qidx[NQ];

    const int tid = threadIdx.x;
    const int b   = blockIdx.x >> 2;      // / NCHUNK
    const int c   = blockIdx.x & 3;       // % NCHUNK

    // ---- stage question indices, then gather q into LDS ----
    if (tid < NQ) qidx[tid] = questions[b * NQ + tid];
    __syncthreads();
    for (int i = tid; i < NQ * DD / 4; i += 256) {   // 576 float4
        const int j  = i >> 5;          // / (DD/4)
        const int d4 = i & 31;
        ((float4*)q_lds)[i] = ((const float4*)(q_emb + (size_t)qidx[j] * DD))[d4];
    }
    __syncthreads();

    // ---- QK: thread-per-row, 2 rows/thread (r=tid, tid+256) ----
    {
        const size_t rowbase = (size_t)b * SS + (size_t)c * CHUNK;
        const float4* xr0 = (const float4*)(x + (rowbase + tid) * DD);
        const float4* xr1 = (const float4*)(x + (rowbase + tid + 256) * DD);
        const float4* q4  = (const float4*)q_lds;

        float acc0[NQ], acc1[NQ];
        #pragma unroll
        for (int j = 0; j < NQ; ++j) { acc0[j] = 0.f; acc1[j] = 0.f; }

        #pragma unroll 2
        for (int d4 = 0; d4 < DD / 4; ++d4) {
            const float4 xa = xr0[d4];
            const float4 xb = xr1[d4];
            #pragma unroll
            for (int j = 0; j < NQ; ++j) {
                const float4 qv = q4[j * 32 + d4];   // wave-uniform -> LDS broadcast
                acc0[j] = fmaf(xa.x, qv.x, fmaf(xa.y, qv.y, fmaf(xa.z, qv.z, fmaf(xa.w, qv.w, acc0[j]))));
                acc1[j] = fmaf(xb.x, qv.x, fmaf(xb.y, qv.y, fmaf(xb.z, qv.z, fmaf(xb.w, qv.w, acc1[j]))));
            }
        }
        const int m0 = mask[rowbase + tid];
        const int m1 = mask[rowbase + tid + 256];
        #pragma unroll
        for (int j = 0; j < NQ; ++j) {
            s_lds[j * CHUNK + tid]       = m0 ? acc0[j] * SCALE : -1e30f;
            s_lds[j * CHUNK + tid + 256] = m1 ? acc1[j] * SCALE : -1e30f;
        }
    }
    __syncthreads();

    // ---- partial softmax per query row: m, l, p written back in place ----
    const int wv   = tid >> 6;
    const int lane = tid & 63;
    float* recp = ws + (size_t)(b * NCHUNK + c) * REC_F;

    for (int j = wv; j < NQ; j += 4) {
        float v[8];
        float m = -1e30f;
        #pragma unroll
        for (int k = 0; k < 8; ++k) {
            v[k] = s_lds[j * CHUNK + lane + k * 64];
            m = fmaxf(m, v[k]);
        }
        #pragma unroll
        for (int off = 32; off > 0; off >>= 1) m = fmaxf(m, __shfl_xor(m, off));
        float sum = 0.f;
        #pragma unroll
        for (int k = 0; k < 8; ++k) {
            const float p = (v[k] <= -1e29f) ? 0.f : __expf(v[k] - m);
            s_lds[j * CHUNK + lane + k * 64] = p;
            sum += p;
        }
        #pragma unroll
        for (int off = 32; off > 0; off >>= 1) sum += __shfl_xor(sum, off);
        if (lane == 0) { recp[j] = m; recp[NQ + j] = sum; }
    }
    __syncthreads();

    // ---- PV: thread-per-(2 d-cols, 4-5 queries); x re-read coalesced ----
    {
        const int d2 = lane * 2;
        const int nj = (wv < 2) ? 5 : 4;          // queries j = wv, wv+4, ...
        float a0[5] = {0.f, 0.f, 0.f, 0.f, 0.f};
        float a1[5] = {0.f, 0.f, 0.f, 0.f, 0.f};
        const float* xb = x + ((size_t)b * SS + (size_t)c * CHUNK) * DD;

        for (int r0 = 0; r0 < CHUNK; r0 += 4) {
            const float2 x0 = *(const float2*)(xb + (size_t)(r0 + 0) * DD + d2);
            const float2 x1 = *(const float2*)(xb + (size_t)(r0 + 1) * DD + d2);
            const float2 x2 = *(const float2*)(xb + (size_t)(r0 + 2) * DD + d2);
            const float2 x3 = *(const float2*)(xb + (size_t)(r0 + 3) * DD + d2);
            #pragma unroll
            for (int jj = 0; jj < 5; ++jj) {
                if (jj < nj) {
                    const int j = wv + jj * 4;
                    const float4 p4 = *(const float4*)&s_lds[j * CHUNK + r0]; // uniform broadcast
                    a0[jj] = fmaf(p4.x, x0.x, a0[jj]);
                    a0[jj] = fmaf(p4.y, x1.x, a0[jj]);
                    a0[jj] = fmaf(p4.z, x2.x, a0[jj]);
                    a0[jj] = fmaf(p4.w, x3.x, a0[jj]);
                    a1[jj] = fmaf(p4.x, x0.y, a1[jj]);
                    a1[jj] = fmaf(p4.y, x1.y, a1[jj]);
                    a1[jj] = fmaf(p4.z, x2.y, a1[jj]);
                    a1[jj] = fmaf(p4.w, x3.y, a1[jj]);
                }
            }
        }
        float* accp = recp + ACC_OFF;
        #pragma unroll
        for (int jj = 0; jj < 5; ++jj) {
            if (jj < nj) {
                const int j = wv + jj * 4;
                *(float2*)(accp + j * DD + d2) = make_float2(a0[jj], a1[jj]);
            }
        }
    }
}

// one wave per (b, j): merge NCHUNK partials, normalize, write out
__global__ __launch_bounds__(256) void ap_combine(
    const float* __restrict__ ws, float* __restrict__ out)
{
    const int lane = threadIdx.x & 63;
    const int wv   = threadIdx.x >> 6;
    const int pair = blockIdx.x * 4 + wv;     // < B*NQ = 2304
    const int b = pair / NQ;
    const int j = pair % NQ;

    float mc[NCHUNK], lc[NCHUNK];
    float M = -1e30f;
    #pragma unroll
    for (int c = 0; c < NCHUNK; ++c) {
        const float* recp = ws + (size_t)(b * NCHUNK + c) * REC_F;
        mc[c] = recp[j];
        lc[c] = recp[NQ + j];
        M = fmaxf(M, mc[c]);
    }
    float L = 0.f;
    float w[NCHUNK];
    #pragma unroll
    for (int c = 0; c < NCHUNK; ++c) {
        w[c] = (lc[c] > 0.f) ? __expf(mc[c] - M) : 0.f;
        L = fmaf(lc[c], w[c], L);
    }
    const float inv = 1.0f / L;

    float o0 = 0.f, o1 = 0.f;
    #pragma unroll
    for (int c = 0; c < NCHUNK; ++c) {
        const float* accp = ws + (size_t)(b * NCHUNK + c) * REC_F + ACC_OFF + j * DD;
        o0 = fmaf(w[c], accp[lane],      o0);
        o1 = fmaf(w[c], accp[lane + 64], o1);
    }
    float* op = out + ((size_t)b * NQ + j) * DD;
    op[lane]      = o0 * inv;
    op[lane + 64] = o1 * inv;
}

extern "C" void kernel_launch(void* const* d_in, const int* in_sizes, int n_in,
                              void* d_out, int out_size, void* d_ws, size_t ws_size,
                              hipStream_t stream)
{
    const float* x         = (const float*)d_in[0];
    const float* q_emb     = (const float*)d_in[1];
    const int*   questions = (const int*)d_in[2];
    const int*   mask      = (const int*)d_in[3];
    float* out = (float*)d_out;
    float* ws  = (float*)d_ws;   // needs 512 * 2340 * 4 B = 4.6 MB

    hipLaunchKernelGGL(ap_partial, dim3(BB * NCHUNK), dim3(256), 0, stream,
                       x, q_emb, questions, mask, ws);
    hipLaunchKernelGGL(ap_combine, dim3(BB * NQ / 4), dim3(256), 0, stream,
                       ws, out);
}

// Round 2
// 237.357 us; speedup vs baseline: 1.0842x; 1.0842x over previous
//
#include <hip/hip_runtime.h>
#include <math.h>

// AttentionPooling: B=128, S=2048, D=128, NQ=18, QDIM=100 (fp32)
// R2: 512-thread blocks (8 waves) for 16 waves/CU occupancy; CHUNK=512,
// grid=512, ws layout unchanged (4.79 MB). PV split by half-chunk per wave,
// partials reduced through reused q_lds.

#define BB 128
#define SS 2048
#define DD 128
#define NQ 18
#define NCHUNK 4
#define CHUNK 512            // SS / NCHUNK
#define SCALE 0.08838834764831845f   // 1/sqrt(128)
#define REC_F (NQ * 2 + NQ * DD)     // per-(b,c) record: m[18], l[18], acc[18][128]
#define ACC_OFF (NQ * 2)

__global__ __launch_bounds__(512) void ap_partial(
    const float* __restrict__ x, const float* __restrict__ q_emb,
    const int* __restrict__ questions, const int* __restrict__ mask,
    float* __restrict__ ws)
{
    __shared__ float q_lds[NQ * DD];      // 9 KB (reused as PV partial buffer)
    __shared__ float s_lds[NQ * CHUNK];   // 36 KB
    __shared__ int   qidx[NQ];

    const int tid = threadIdx.x;
    const int b   = blockIdx.x >> 2;      // / NCHUNK
    const int c   = blockIdx.x & 3;       // % NCHUNK
    const size_t rowbase = (size_t)b * SS + (size_t)c * CHUNK;

    // ---- stage question indices, then gather q into LDS ----
    if (tid < NQ) qidx[tid] = questions[b * NQ + tid];
    __syncthreads();
    for (int i = tid; i < NQ * DD / 4; i += 512) {   // 576 float4
        const int j  = i >> 5;          // / (DD/4)
        const int d4 = i & 31;
        ((float4*)q_lds)[i] = ((const float4*)(q_emb + (size_t)qidx[j] * DD))[d4];
    }
    __syncthreads();

    // ---- QK: thread-per-row, 1 row/thread (512 rows, 512 threads) ----
    {
        const int m0 = mask[rowbase + tid];          // issue early
        const float4* xr0 = (const float4*)(x + (rowbase + tid) * DD);
        const float4* q4  = (const float4*)q_lds;

        float acc0[NQ];
        #pragma unroll
        for (int j = 0; j < NQ; ++j) acc0[j] = 0.f;

        #pragma unroll 4
        for (int d4 = 0; d4 < DD / 4; ++d4) {
            const float4 xa = xr0[d4];
            #pragma unroll
            for (int j = 0; j < NQ; ++j) {
                const float4 qv = q4[j * 32 + d4];   // wave-uniform -> LDS broadcast
                acc0[j] = fmaf(xa.x, qv.x, fmaf(xa.y, qv.y, fmaf(xa.z, qv.z, fmaf(xa.w, qv.w, acc0[j]))));
            }
        }
        #pragma unroll
        for (int j = 0; j < NQ; ++j)
            s_lds[j * CHUNK + tid] = m0 ? acc0[j] * SCALE : -1e30f;
    }
    __syncthreads();

    // ---- partial softmax per query row (8 waves x rows {wv, wv+8, wv+16}) ----
    const int wv   = tid >> 6;
    const int lane = tid & 63;
    float* recp = ws + (size_t)(b * NCHUNK + c) * REC_F;

    for (int j = wv; j < NQ; j += 8) {
        float v[8];
        float m = -1e30f;
        #pragma unroll
        for (int k = 0; k < 8; ++k) {
            v[k] = s_lds[j * CHUNK + lane + k * 64];
            m = fmaxf(m, v[k]);
        }
        #pragma unroll
        for (int off = 32; off > 0; off >>= 1) m = fmaxf(m, __shfl_xor(m, off));
        float sum = 0.f;
        #pragma unroll
        for (int k = 0; k < 8; ++k) {
            const float p = (v[k] <= -1e29f) ? 0.f : __expf(v[k] - m);
            s_lds[j * CHUNK + lane + k * 64] = p;
            sum += p;
        }
        #pragma unroll
        for (int off = 32; off > 0; off >>= 1) sum += __shfl_xor(sum, off);
        if (lane == 0) { recp[j] = m; recp[NQ + j] = sum; }
    }
    __syncthreads();

    // ---- PV: wave -> (half-chunk h, query set qb); x re-read coalesced ----
    // wave wv: h = wv&1 (rows [h*256, h*256+256)), qb = wv>>1,
    // queries j = qb + 4*jj, nj = 5 for qb<2 else 4.
    {
        const int h  = wv & 1;
        const int qb = wv >> 1;
        const int nj = (qb < 2) ? 5 : 4;
        const int d2 = lane * 2;
        const int r_base = h * 256;

        float a0[5] = {0.f, 0.f, 0.f, 0.f, 0.f};
        float a1[5] = {0.f, 0.f, 0.f, 0.f, 0.f};
        const float* xb = x + (rowbase + r_base) * DD;

        for (int r0 = 0; r0 < 256; r0 += 4) {
            const float2 x0 = *(const float2*)(xb + (size_t)(r0 + 0) * DD + d2);
            const float2 x1 = *(const float2*)(xb + (size_t)(r0 + 1) * DD + d2);
            const float2 x2 = *(const float2*)(xb + (size_t)(r0 + 2) * DD + d2);
            const float2 x3 = *(const float2*)(xb + (size_t)(r0 + 3) * DD + d2);
            #pragma unroll
            for (int jj = 0; jj < 5; ++jj) {
                if (jj < nj) {
                    const int j = qb + jj * 4;
                    const float4 p4 = *(const float4*)&s_lds[j * CHUNK + r_base + r0]; // uniform broadcast
                    a0[jj] = fmaf(p4.x, x0.x, a0[jj]);
                    a0[jj] = fmaf(p4.y, x1.x, a0[jj]);
                    a0[jj] = fmaf(p4.z, x2.x, a0[jj]);
                    a0[jj] = fmaf(p4.w, x3.x, a0[jj]);
                    a1[jj] = fmaf(p4.x, x0.y, a1[jj]);
                    a1[jj] = fmaf(p4.y, x1.y, a1[jj]);
                    a1[jj] = fmaf(p4.z, x2.y, a1[jj]);
                    a1[jj] = fmaf(p4.w, x3.y, a1[jj]);
                }
            }
        }

        // half h==1 parks its partials in q_lds (QK no longer needs q)
        if (h == 1) {
            #pragma unroll
            for (int jj = 0; jj < 5; ++jj) {
                if (jj < nj) {
                    const int j = qb + jj * 4;
                    *(float2*)(q_lds + j * DD + d2) = make_float2(a0[jj], a1[jj]);
                }
            }
        }
        __syncthreads();
        if (h == 0) {
            float* accp = recp + ACC_OFF;
            #pragma unroll
            for (int jj = 0; jj < 5; ++jj) {
                if (jj < nj) {
                    const int j = qb + jj * 4;
                    const float2 o = *(const float2*)(q_lds + j * DD + d2);
                    *(float2*)(accp + j * DD + d2) = make_float2(a0[jj] + o.x, a1[jj] + o.y);
                }
            }
        }
    }
}

// one wave per (b, j): merge NCHUNK partials, normalize, write out
__global__ __launch_bounds__(256) void ap_combine(
    const float* __restrict__ ws, float* __restrict__ out)
{
    const int lane = threadIdx.x & 63;
    const int wv   = threadIdx.x >> 6;
    const int pair = blockIdx.x * 4 + wv;     // < B*NQ = 2304
    const int b = pair / NQ;
    const int j = pair % NQ;

    float mc[NCHUNK], lc[NCHUNK];
    float M = -1e30f;
    #pragma unroll
    for (int c = 0; c < NCHUNK; ++c) {
        const float* recp = ws + (size_t)(b * NCHUNK + c) * REC_F;
        mc[c] = recp[j];
        lc[c] = recp[NQ + j];
        M = fmaxf(M, mc[c]);
    }
    float L = 0.f;
    float w[NCHUNK];
    #pragma unroll
    for (int c = 0; c < NCHUNK; ++c) {
        w[c] = (lc[c] > 0.f) ? __expf(mc[c] - M) : 0.f;
        L = fmaf(lc[c], w[c], L);
    }
    const float inv = 1.0f / L;

    float o0 = 0.f, o1 = 0.f;
    #pragma unroll
    for (int c = 0; c < NCHUNK; ++c) {
        const float* accp = ws + (size_t)(b * NCHUNK + c) * REC_F + ACC_OFF + j * DD;
        o0 = fmaf(w[c], accp[lane],      o0);
        o1 = fmaf(w[c], accp[lane + 64], o1);
    }
    float* op = out + ((size_t)b * NQ + j) * DD;
    op[lane]      = o0 * inv;
    op[lane + 64] = o1 * inv;
}

extern "C" void kernel_launch(void* const* d_in, const int* in_sizes, int n_in,
                              void* d_out, int out_size, void* d_ws, size_t ws_size,
                              hipStream_t stream)
{
    const float* x         = (const float*)d_in[0];
    const float* q_emb     = (const float*)d_in[1];
    const int*   questions = (const int*)d_in[2];
    const int*   mask      = (const int*)d_in[3];
    float* out = (float*)d_out;
    float* ws  = (float*)d_ws;   // 512 * 2340 * 4 B = 4.79 MB

    hipLaunchKernelGGL(ap_partial, dim3(BB * NCHUNK), dim3(512), 0, stream,
                       x, q_emb, questions, mask, ws);
    hipLaunchKernelGGL(ap_combine, dim3(BB * NQ / 4), dim3(256), 0, stream,
                       ws, out);
}